// Round 6
// baseline (1157.827 us; speedup 1.0000x reference)
//
#include <hip/hip_runtime.h>

typedef unsigned short ushort_t;
typedef __attribute__((ext_vector_type(8))) short short8;
typedef __attribute__((ext_vector_type(4))) unsigned short ushort4_t;
typedef __attribute__((ext_vector_type(4))) float f32x4;

#define NH 32
#define NHK 8
#define HD 128
#define HID 4096
#define NB 2
#define SEQ 2048
#define NQKV ((NH + 2 * NHK) * HD)  // 6144

static __device__ inline ushort_t f2bu(float x) {
  unsigned u = __builtin_bit_cast(unsigned, x);
  unsigned r = (u + 0x7FFFu + ((u >> 16) & 1u)) >> 16;  // RNE
  return (ushort_t)r;
}

// async global->LDS, 16B per lane. LDS dest = wave-uniform base + lane*16.
typedef __attribute__((address_space(1))) void gvoid;
typedef __attribute__((address_space(3))) void lvoid;
static __device__ inline void gld16(const void* g, void* l) {
  __builtin_amdgcn_global_load_lds((gvoid*)g, (lvoid*)l, 16, 0, 0);
}

// ---------- RoPE cos/sin table: tab[s][d] = {cos,sin}(pos[s]*10000^(-d/64)) --
// Lives in the (then-dead) attno region: zero extra ws. Regenerated per batch.
__global__ void rope_tab_k(const int* __restrict__ positions, float* __restrict__ tab) {
  int i = blockIdx.x * 256 + threadIdx.x;  // [0, SEQ*64)
  int s = i >> 6, d = i & 63;
  float pos = (float)positions[s];
  float f = pos * exp2f(-0.20762050593046014f * (float)d);
  tab[2 * i] = cosf(f);
  tab[2 * i + 1] = sinf(f);
}

// ---------- fp32 -> bf16 bulk convert (hidden states) ------------------------
__global__ void h2b_k(const float* __restrict__ in, ushort_t* __restrict__ out) {
  long i = ((long)blockIdx.x * 256 + threadIdx.x) * 8;
  f32x4 a = *(const f32x4*)&in[i];
  f32x4 b = *(const f32x4*)&in[i + 4];
  ushort4_t ya, yb;
#pragma unroll
  for (int u = 0; u < 4; ++u) { ya[u] = f2bu(a[u]); yb[u] = f2bu(b[u]); }
  *(ushort4_t*)&out[i] = ya;
  *(ushort4_t*)&out[i + 4] = yb;
}

// ---------- weight transpose+convert: out[n][k] bf16 <- in[k][n] f32 ---------
__global__ void wt_k(const float* __restrict__ in, ushort_t* __restrict__ out,
                     int K, int N) {
  __shared__ ushort_t T[64][72];  // [k][n] bf16, +8 pad
  int n0 = blockIdx.x * 64, k0 = blockIdx.y * 64;
  int t = threadIdx.x;
  int kr = t >> 4, nc = (t & 15) * 4;
#pragma unroll
  for (int p = 0; p < 4; ++p) {
    int k = kr + p * 16;
    f32x4 x = *(const f32x4*)&in[(long)(k0 + k) * N + n0 + nc];
    ushort4_t y;
#pragma unroll
    for (int u = 0; u < 4; ++u) y[u] = f2bu(x[u]);
    *(ushort4_t*)&T[k][nc] = y;
  }
  __syncthreads();
  int n = t >> 2, kc = (t & 3) * 16;
  ushort_t tmp[16];
#pragma unroll
  for (int j = 0; j < 16; ++j) tmp[j] = T[kc + j][n];
  *(short8*)&out[(long)(n0 + n) * K + k0 + kc] = *(short8*)&tmp[0];
  *(short8*)&out[(long)(n0 + n) * K + k0 + kc + 8] = *(short8*)&tmp[8];
}

// ---------------------------------------------------------------------------
// gemm_bt: C[M,N] = A[M,K] @ Bt[N,K]^T, both bf16.
// 2-phase double-buffered K-loop (T3-minimum): stage tile t+1 via
// global_load_lds BEFORE computing tile t; single __syncthreads per K-step
// (its vmcnt(0) lands after ds_read+MFMA, so loads get the whole compute
// phase to fly). Previous 2-barrier version drained vmcnt(0) immediately
// after issue: MfmaUtil 20%, 210 us. Source-side XOR swizzle on 16B
// granules; swizzled ds_read_b128 (2-way = free). Wave tile 32x128.
// ---------------------------------------------------------------------------
template <int MODE>
__global__ __attribute__((amdgpu_flat_work_group_size(256, 256),
                          amdgpu_waves_per_eu(2, 2)))
void gemm_bt(const ushort_t* __restrict__ A,
             const ushort_t* __restrict__ Bt,
             float* __restrict__ C,
             const float* __restrict__ tab,
             ushort_t* __restrict__ Qo,
             ushort_t* __restrict__ Ko,
             ushort_t* __restrict__ Vo,
             int M, int N, int K) {
  __shared__ ushort_t As[2][128 * 32];  // 2 x 8 KB, granule-swizzled
  __shared__ ushort_t Bs[2][128 * 32];  // 2 x 8 KB
  int m0 = blockIdx.y * 128, n0 = blockIdx.x * 128;
  int tid = threadIdx.x;
  int lane = tid & 63, wave = tid >> 6;
  int wm = wave * 32;
  int l15 = lane & 15, quad = lane >> 4;
  f32x4 acc[2][8];
#pragma unroll
  for (int i = 0; i < 2; ++i)
#pragma unroll
    for (int j = 0; j < 8; ++j) acc[i][j] = (f32x4){0.f, 0.f, 0.f, 0.f};

  int iw = wave * 2;
  int r0 = iw * 16 + (lane >> 2);          // first staged row for this lane
  int gk0 = ((lane & 3) ^ ((r0 >> 1) & 3)) * 8;
  int r1 = r0 + 16;
  int gk1 = ((lane & 3) ^ ((r1 >> 1) & 3)) * 8;

#define STAGE(buf, k0)                                                   \
  do {                                                                   \
    gld16(&A[(long)(m0 + r0) * K + (k0) + gk0], &As[buf][iw * 512]);     \
    gld16(&Bt[(long)(n0 + r0) * K + (k0) + gk0], &Bs[buf][iw * 512]);    \
    gld16(&A[(long)(m0 + r1) * K + (k0) + gk1], &As[buf][iw * 512 + 512]); \
    gld16(&Bt[(long)(n0 + r1) * K + (k0) + gk1], &Bs[buf][iw * 512 + 512]); \
  } while (0)

  int NT = K >> 5;
  STAGE(0, 0);
  __syncthreads();  // drain tile-0 loads (once)
  int cur = 0;
  for (int t = 0; t < NT; ++t) {
    if (t + 1 < NT) STAGE(cur ^ 1, (t + 1) << 5);  // async, overlaps compute
    short8 af[2], bfr[8];
#pragma unroll
    for (int i = 0; i < 2; ++i) {
      int r = wm + i * 16 + l15;
      af[i] = *(short8*)&As[cur][r * 32 + ((quad ^ ((r >> 1) & 3)) << 3)];
    }
#pragma unroll
    for (int j = 0; j < 8; ++j) {
      int r = j * 16 + l15;
      bfr[j] = *(short8*)&Bs[cur][r * 32 + ((quad ^ ((r >> 1) & 3)) << 3)];
    }
#pragma unroll
    for (int i = 0; i < 2; ++i)
#pragma unroll
      for (int j = 0; j < 8; ++j)
        acc[i][j] = __builtin_amdgcn_mfma_f32_16x16x32_bf16(af[i], bfr[j], acc[i][j], 0, 0, 0);
    __syncthreads();  // drains next-tile loads; fences reads of buf[cur]
    cur ^= 1;
  }
#undef STAGE

  if (MODE == 0) {
#pragma unroll
    for (int i = 0; i < 2; ++i)
#pragma unroll
      for (int j = 0; j < 8; ++j)
#pragma unroll
        for (int r = 0; r < 4; ++r) {
          int row = m0 + wm + i * 16 + quad * 4 + r;
          int col = n0 + j * 16 + l15;
          C[(long)row * N + col] = acc[i][j][r];
        }
  } else {
    int head = n0 >> 7;  // 0..31 q, 32..39 k, 40..47 v (block-uniform)
    const float2* tb = (const float2*)tab;
    if (head < NH + NHK) {
      bool isq = head < NH;
      ushort_t* dst = isq ? (Qo + (long)head * SEQ * HD)
                          : (Ko + (long)(head - NH) * SEQ * HD);
      float sc = isq ? 0.08838834764831845f : 1.0f;  // fold 128^-0.5 into Q
#pragma unroll
      for (int i = 0; i < 2; ++i)
#pragma unroll
        for (int r = 0; r < 4; ++r) {
          int s = m0 + wm + i * 16 + quad * 4 + r;
#pragma unroll
          for (int j = 0; j < 4; ++j) {
            int d = j * 16 + l15;  // 0..63
            float2 cs = tb[s * 64 + d];
            float x1 = acc[i][j][r], x2 = acc[i][j + 4][r];
            dst[(long)s * HD + d] = f2bu((x1 * cs.x - x2 * cs.y) * sc);
            dst[(long)s * HD + d + 64] = f2bu((x2 * cs.x + x1 * cs.y) * sc);
          }
        }
    } else {
      int hk = head - NH - NHK;
      ushort_t* dst = Vo + (long)hk * HD * SEQ;  // V^T: [D][S]
#pragma unroll
      for (int i = 0; i < 2; ++i)
#pragma unroll
        for (int j = 0; j < 8; ++j)
#pragma unroll
          for (int r = 0; r < 4; ++r) {
            int s = m0 + wm + i * 16 + quad * 4 + r;
            int d = j * 16 + l15;
            dst[(long)d * SEQ + s] = f2bu(acc[i][j][r]);
          }
    }
  }
}

// ---------------------------------------------------------------------------
// Fallback GEMM (fp32 B transposed in-kernel) — used only if ws too small.
// ---------------------------------------------------------------------------
template <int MODE, typename TA>
__global__ __attribute__((amdgpu_flat_work_group_size(256, 256),
                          amdgpu_waves_per_eu(2, 2)))
void gemm_kn(const TA* __restrict__ A,
             const float* __restrict__ B,
             float* __restrict__ C,
             const float* __restrict__ tab,
             ushort_t* __restrict__ Qo,
             ushort_t* __restrict__ Ko,
             ushort_t* __restrict__ Vo,
             int M, int N, int K) {
  __shared__ ushort_t As[128][40];
  __shared__ ushort_t Bs[128 * 32];
  int m0 = blockIdx.y * 128, n0 = blockIdx.x * 128;
  int tid = threadIdx.x;
  int lane = tid & 63, wave = tid >> 6;
  int wm = wave * 32;
  int l15 = lane & 15, quad = lane >> 4;
  f32x4 acc[2][8];
#pragma unroll
  for (int i = 0; i < 2; ++i)
#pragma unroll
    for (int j = 0; j < 8; ++j) acc[i][j] = (f32x4){0.f, 0.f, 0.f, 0.f};

  for (int k0 = 0; k0 < K; k0 += 32) {
    __syncthreads();
    if constexpr (sizeof(TA) == 2) {
#pragma unroll
      for (int it = 0; it < 2; ++it) {
        int v = tid + it * 256;
        int row = v >> 2, kc = (v & 3) * 8;
        *(short8*)&As[row][kc] =
            *(const short8*)&A[(long)(m0 + row) * K + k0 + kc];
      }
    } else {
#pragma unroll
      for (int it = 0; it < 4; ++it) {
        int v = tid + it * 256;
        int row = v >> 3, kc = (v & 7) * 4;
        f32x4 x = *(const f32x4*)&A[(long)(m0 + row) * K + k0 + kc];
        ushort4_t y;
#pragma unroll
        for (int u = 0; u < 4; ++u) y[u] = f2bu(x[u]);
        *(ushort4_t*)&As[row][kc] = y;
      }
    }
#pragma unroll
    for (int it = 0; it < 4; ++it) {
      int v = tid + it * 256;
      int kr = v >> 5, nc = (v & 31) * 4;
      f32x4 x = *(const f32x4*)&B[(long)(k0 + kr) * N + n0 + nc];
      int kg = (kr >> 3) << 3, ke = kr & 7;
#pragma unroll
      for (int u = 0; u < 4; ++u) {
        int n = nc + u;
        Bs[n * 32 + ((kg ^ (((n >> 2) & 3) << 3))) + ke] = f2bu(x[u]);
      }
    }
    __syncthreads();
    short8 af[2], bfr[8];
#pragma unroll
    for (int i = 0; i < 2; ++i) af[i] = *(short8*)&As[wm + i * 16 + l15][quad * 8];
#pragma unroll
    for (int j = 0; j < 8; ++j) {
      int n = j * 16 + l15;
      bfr[j] = *(short8*)&Bs[n * 32 + ((quad ^ ((n >> 2) & 3)) << 3)];
    }
#pragma unroll
    for (int i = 0; i < 2; ++i)
#pragma unroll
      for (int j = 0; j < 8; ++j)
        acc[i][j] = __builtin_amdgcn_mfma_f32_16x16x32_bf16(af[i], bfr[j], acc[i][j], 0, 0, 0);
  }

  if (MODE == 0) {
#pragma unroll
    for (int i = 0; i < 2; ++i)
#pragma unroll
      for (int j = 0; j < 8; ++j)
#pragma unroll
        for (int r = 0; r < 4; ++r) {
          int row = m0 + wm + i * 16 + quad * 4 + r;
          int col = n0 + j * 16 + l15;
          C[(long)row * N + col] = acc[i][j][r];
        }
  } else {
    int head = n0 >> 7;
    const float2* tb = (const float2*)tab;
    if (head < NH + NHK) {
      bool isq = head < NH;
      ushort_t* dst = isq ? (Qo + (long)head * SEQ * HD)
                          : (Ko + (long)(head - NH) * SEQ * HD);
      float sc = isq ? 0.08838834764831845f : 1.0f;
#pragma unroll
      for (int i = 0; i < 2; ++i)
#pragma unroll
        for (int r = 0; r < 4; ++r) {
          int s = m0 + wm + i * 16 + quad * 4 + r;
#pragma unroll
          for (int j = 0; j < 4; ++j) {
            int d = j * 16 + l15;
            float2 cs = tb[s * 64 + d];
            float x1 = acc[i][j][r], x2 = acc[i][j + 4][r];
            dst[(long)s * HD + d] = f2bu((x1 * cs.x - x2 * cs.y) * sc);
            dst[(long)s * HD + d + 64] = f2bu((x2 * cs.x + x1 * cs.y) * sc);
          }
        }
    } else {
      int hk = head - NH - NHK;
      ushort_t* dst = Vo + (long)hk * HD * SEQ;
#pragma unroll
      for (int i = 0; i < 2; ++i)
#pragma unroll
        for (int j = 0; j < 8; ++j)
#pragma unroll
          for (int r = 0; r < 4; ++r) {
            int s = m0 + wm + i * 16 + quad * 4 + r;
            int d = j * 16 + l15;
            dst[(long)d * SEQ + s] = f2bu(acc[i][j][r]);
          }
    }
  }
}

// ---------- flash attention: 64 q / block (4 waves x 16), 64-key chunks ------
// KVBLK=64 + LPT (heaviest causal blocks first).
__global__ __launch_bounds__(256, 2) void attn_k(const ushort_t* __restrict__ Q,
                                                 const ushort_t* __restrict__ Kg,
                                                 const ushort_t* __restrict__ Vt,
                                                 ushort_t* __restrict__ Aout) {
  __shared__ ushort_t Ks[64][136];    // [key][d]   (+8 pad)
  __shared__ ushort_t Vs[128][72];    // [d][key]   (+8 pad)
  __shared__ ushort_t Ps[4][16][72];  // per-wave P tile [q][key] (+8 pad)
  int qt = ((int)gridDim.x - 1 - blockIdx.x) * 64;  // LPT order
  int h = blockIdx.y;
  int hk = h >> 2;
  const ushort_t* Qh = Q + (long)h * SEQ * HD;
  const ushort_t* Kh = Kg + (long)hk * SEQ * HD;
  const ushort_t* Vh = Vt + (long)hk * HD * SEQ;
  int tid = threadIdx.x, lane = tid & 63, wave = tid >> 6;
  int l15 = lane & 15, quad = lane >> 4;
  int qw = qt + wave * 16;
  short8 qf[4];
#pragma unroll
  for (int c = 0; c < 4; ++c)
    qf[c] = *(const short8*)&Qh[(long)(qw + l15) * HD + c * 32 + quad * 8];
  f32x4 O[8];
#pragma unroll
  for (int dt = 0; dt < 8; ++dt) O[dt] = (f32x4){0.f, 0.f, 0.f, 0.f};
  float mrow[4], lrow[4];
#pragma unroll
  for (int r = 0; r < 4; ++r) { mrow[r] = -1e30f; lrow[r] = 0.f; }
  int kend = qt + 64;
  for (int kc = 0; kc < kend; kc += 64) {
    __syncthreads();
#pragma unroll
    for (int i = 0; i < 4; ++i) {
      int v = tid + i * 256;
      int kr = v >> 4, dc = (v & 15) * 8;
      *(short8*)&Ks[kr][dc] = *(const short8*)&Kh[(long)(kc + kr) * HD + dc];
    }
#pragma unroll
    for (int i = 0; i < 4; ++i) {
      int v = tid + i * 256;
      int dr = v >> 3, kcol = (v & 7) * 8;
      *(short8*)&Vs[dr][kcol] = *(const short8*)&Vh[(long)dr * SEQ + kc + kcol];
    }
    __syncthreads();
    bool active = (kc <= qw + 15);  // wave-uniform
    if (active) {
      f32x4 S[4];
#pragma unroll
      for (int t = 0; t < 4; ++t) S[t] = (f32x4){0.f, 0.f, 0.f, 0.f};
#pragma unroll
      for (int c = 0; c < 4; ++c) {
#pragma unroll
        for (int t = 0; t < 4; ++t) {
          short8 kf = *(short8*)&Ks[t * 16 + l15][c * 32 + quad * 8];
          S[t] = __builtin_amdgcn_mfma_f32_16x16x32_bf16(qf[c], kf, S[t], 0, 0, 0);
        }
      }
#pragma unroll
      for (int r = 0; r < 4; ++r) {
        int qrow = qw + quad * 4 + r;
        float vv[4];
#pragma unroll
        for (int t = 0; t < 4; ++t)
          vv[t] = (kc + t * 16 + l15 <= qrow) ? S[t][r] : -1e30f;
        float mx = fmaxf(fmaxf(vv[0], vv[1]), fmaxf(vv[2], vv[3]));
        mx = fmaxf(mx, __shfl_xor(mx, 1, 64));
        mx = fmaxf(mx, __shfl_xor(mx, 2, 64));
        mx = fmaxf(mx, __shfl_xor(mx, 4, 64));
        mx = fmaxf(mx, __shfl_xor(mx, 8, 64));
        float mnew = fmaxf(mrow[r], mx);
        float alpha = __expf(mrow[r] - mnew);
        float p[4];
#pragma unroll
        for (int t = 0; t < 4; ++t) p[t] = __expf(vv[t] - mnew);
        float rs = (p[0] + p[1]) + (p[2] + p[3]);
        rs += __shfl_xor(rs, 1, 64);
        rs += __shfl_xor(rs, 2, 64);
        rs += __shfl_xor(rs, 4, 64);
        rs += __shfl_xor(rs, 8, 64);
        lrow[r] = lrow[r] * alpha + rs;
        mrow[r] = mnew;
#pragma unroll
        for (int dt = 0; dt < 8; ++dt) O[dt][r] *= alpha;
#pragma unroll
        for (int t = 0; t < 4; ++t)
          Ps[wave][quad * 4 + r][t * 16 + l15] = f2bu(p[t]);
      }
    }
    __syncthreads();
    if (active) {
      short8 pf0 = *(short8*)&Ps[wave][l15][quad * 8];
      short8 pf1 = *(short8*)&Ps[wave][l15][32 + quad * 8];
#pragma unroll
      for (int dt = 0; dt < 8; ++dt) {
        short8 vf0 = *(short8*)&Vs[dt * 16 + l15][quad * 8];
        short8 vf1 = *(short8*)&Vs[dt * 16 + l15][32 + quad * 8];
        O[dt] = __builtin_amdgcn_mfma_f32_16x16x32_bf16(pf0, vf0, O[dt], 0, 0, 0);
        O[dt] = __builtin_amdgcn_mfma_f32_16x16x32_bf16(pf1, vf1, O[dt], 0, 0, 0);
      }
    }
  }
#pragma unroll
  for (int dt = 0; dt < 8; ++dt)
#pragma unroll
    for (int r = 0; r < 4; ++r) {
      int q = qw + quad * 4 + r;
      float o = O[dt][r] / lrow[r];
      Aout[(long)q * (NH * HD) + h * HD + dt * 16 + l15] = f2bu(o);
    }
}

extern "C" void kernel_launch(void* const* d_in, const int* in_sizes, int n_in,
                              void* d_out, int out_size, void* d_ws, size_t ws_size,
                              hipStream_t stream) {
  const int* positions = (const int*)d_in[0];
  const float* hidden = (const float*)d_in[1];
  const float* w_qkv = (const float*)d_in[2];
  const float* w_o = (const float*)d_in[3];
  char* ws = (char*)d_ws;
  // Base layout (40 MB, proven):
  ushort_t* Qb = (ushort_t*)(ws + 0L);           // [NH,S,D]   16777216
  ushort_t* Kb = (ushort_t*)(ws + 16777216L);    // [NHK,S,D]   4194304
  ushort_t* Vtb = (ushort_t*)(ws + 20971520L);   // [NHK,D,S]   4194304
  ushort_t* attno = (ushort_t*)(ws + 25165824L); // [S, NH*D]  16777216
  float* tab = (float*)attno;                    // 1 MB, dead before attn_k
  // Extended layout (needs 152 MB total):
  ushort_t* hb16 = (ushort_t*)(ws + 41943040L);   // [NB,S,HID]   33554432
  ushort_t* wqkvT = (ushort_t*)(ws + 75497472L);  // [NQKV,HID]   50331648
  ushort_t* woT = (ushort_t*)(ws + 125829120L);   // [HID,HID]    33554432
  float* outf = (float*)d_out;
  bool big = ws_size >= 159383552ULL;

  if (big) {
    h2b_k<<<dim3((NB * SEQ * HID) / (256 * 8)), 256, 0, stream>>>(hidden, hb16);
    wt_k<<<dim3(NQKV / 64, HID / 64), 256, 0, stream>>>(w_qkv, wqkvT, HID, NQKV);
    wt_k<<<dim3(HID / 64, HID / 64), 256, 0, stream>>>(w_o, woT, HID, HID);
  }
  for (int b = 0; b < NB; ++b) {
    rope_tab_k<<<dim3((SEQ * 64) / 256), 256, 0, stream>>>(positions, tab);
    if (big) {
      gemm_bt<1><<<dim3(NQKV / 128, SEQ / 128), 256, 0, stream>>>(
          hb16 + (long)b * SEQ * HID, wqkvT, nullptr, tab, Qb, Kb, Vtb,
          SEQ, NQKV, HID);
    } else {
      gemm_kn<1, float><<<dim3(NQKV / 128, SEQ / 128), 256, 0, stream>>>(
          hidden + (long)b * SEQ * HID, w_qkv, nullptr, tab, Qb, Kb, Vtb,
          SEQ, NQKV, HID);
    }
    attn_k<<<dim3(SEQ / 64, NH), 256, 0, stream>>>(Qb, Kb, Vtb, attno);
    if (big) {
      gemm_bt<0><<<dim3(HID / 128, SEQ / 128), 256, 0, stream>>>(
          attno, woT, outf + (long)b * SEQ * HID, nullptr, nullptr, nullptr,
          nullptr, SEQ, HID, HID);
    } else {
      gemm_kn<0, ushort_t><<<dim3(HID / 128, SEQ / 128), 256, 0, stream>>>(
          attno, w_o, outf + (long)b * SEQ * HID, nullptr, nullptr, nullptr,
          nullptr, SEQ, HID, HID);
    }
  }
}

// Round 7
// 1013.930 us; speedup vs baseline: 1.1419x; 1.1419x over previous
//
#include <hip/hip_runtime.h>

typedef unsigned short ushort_t;
typedef __attribute__((ext_vector_type(8))) short short8;
typedef __attribute__((ext_vector_type(4))) unsigned short ushort4_t;
typedef __attribute__((ext_vector_type(4))) float f32x4;

#define NH 32
#define NHK 8
#define HD 128
#define HID 4096
#define NB 2
#define SEQ 2048
#define NQKV ((NH + 2 * NHK) * HD)  // 6144

static __device__ inline ushort_t f2bu(float x) {
  unsigned u = __builtin_bit_cast(unsigned, x);
  unsigned r = (u + 0x7FFFu + ((u >> 16) & 1u)) >> 16;  // RNE
  return (ushort_t)r;
}

// async global->LDS, 16B per lane. LDS dest = wave-uniform base + lane*16.
typedef __attribute__((address_space(1))) void gvoid;
typedef __attribute__((address_space(3))) void lvoid;
static __device__ inline void gld16(const void* g, void* l) {
  __builtin_amdgcn_global_load_lds((gvoid*)g, (lvoid*)l, 16, 0, 0);
}

// ---------- RoPE cos/sin table: tab[s][d] = {cos,sin}(pos[s]*10000^(-d/64)) --
// Lives in the (then-dead) attno region: zero extra ws. Regenerated per batch.
__global__ void rope_tab_k(const int* __restrict__ positions, float* __restrict__ tab) {
  int i = blockIdx.x * 256 + threadIdx.x;  // [0, SEQ*64)
  int s = i >> 6, d = i & 63;
  float pos = (float)positions[s];
  float f = pos * exp2f(-0.20762050593046014f * (float)d);
  tab[2 * i] = cosf(f);
  tab[2 * i + 1] = sinf(f);
}

// ---------- fp32 -> bf16 bulk convert (hidden states) ------------------------
__global__ void h2b_k(const float* __restrict__ in, ushort_t* __restrict__ out) {
  long i = ((long)blockIdx.x * 256 + threadIdx.x) * 8;
  f32x4 a = *(const f32x4*)&in[i];
  f32x4 b = *(const f32x4*)&in[i + 4];
  ushort4_t ya, yb;
#pragma unroll
  for (int u = 0; u < 4; ++u) { ya[u] = f2bu(a[u]); yb[u] = f2bu(b[u]); }
  *(ushort4_t*)&out[i] = ya;
  *(ushort4_t*)&out[i + 4] = yb;
}

// ---------- weight transpose+convert: out[n][k] bf16 <- in[k][n] f32 ---------
__global__ void wt_k(const float* __restrict__ in, ushort_t* __restrict__ out,
                     int K, int N) {
  __shared__ ushort_t T[64][72];  // [k][n] bf16, +8 pad
  int n0 = blockIdx.x * 64, k0 = blockIdx.y * 64;
  int t = threadIdx.x;
  int kr = t >> 4, nc = (t & 15) * 4;
#pragma unroll
  for (int p = 0; p < 4; ++p) {
    int k = kr + p * 16;
    f32x4 x = *(const f32x4*)&in[(long)(k0 + k) * N + n0 + nc];
    ushort4_t y;
#pragma unroll
    for (int u = 0; u < 4; ++u) y[u] = f2bu(x[u]);
    *(ushort4_t*)&T[k][nc] = y;
  }
  __syncthreads();
  int n = t >> 2, kc = (t & 3) * 16;
  ushort_t tmp[16];
#pragma unroll
  for (int j = 0; j < 16; ++j) tmp[j] = T[kc + j][n];
  *(short8*)&out[(long)(n0 + n) * K + k0 + kc] = *(short8*)&tmp[0];
  *(short8*)&out[(long)(n0 + n) * K + k0 + kc + 8] = *(short8*)&tmp[8];
}

// ---------------------------------------------------------------------------
// gemm_bt: C[M,N] = A[M,K] @ Bt[N,K]^T, both bf16.
// 2-phase double-buffered K-loop: stage tile t+1 via global_load_lds BEFORE
// computing tile t; single __syncthreads per K-step.
//
// Occupancy history: amdgpu_waves_per_eu(2,2) capped HW occupancy at 2
// waves/EU (measured 17.8% vs 29.7% under launch_bounds(256,2) in round 0);
// counters showed a latency-bound profile (MfmaUtil 20%, VALUBusy 12%,
// HBM 9%, all pipes idle ~65% of cycles) at 1.4 blocks/CU. launch_bounds'
// 2nd arg (min waves/EU) keeps the 256-VGPR budget (no acc spill; VGPR=88)
// WITHOUT the max cap, so LDS(32KB)/VGPR(88) allow ~5 blocks/CU.
// ---------------------------------------------------------------------------
template <int MODE>
__global__ __launch_bounds__(256, 2)
void gemm_bt(const ushort_t* __restrict__ A,
             const ushort_t* __restrict__ Bt,
             float* __restrict__ C,
             const float* __restrict__ tab,
             ushort_t* __restrict__ Qo,
             ushort_t* __restrict__ Ko,
             ushort_t* __restrict__ Vo,
             int M, int N, int K) {
  __shared__ ushort_t As[2][128 * 32];  // 2 x 8 KB, granule-swizzled
  __shared__ ushort_t Bs[2][128 * 32];  // 2 x 8 KB
  int m0 = blockIdx.y * 128, n0 = blockIdx.x * 128;
  int tid = threadIdx.x;
  int lane = tid & 63, wave = tid >> 6;
  int wm = wave * 32;
  int l15 = lane & 15, quad = lane >> 4;
  f32x4 acc[2][8];
#pragma unroll
  for (int i = 0; i < 2; ++i)
#pragma unroll
    for (int j = 0; j < 8; ++j) acc[i][j] = (f32x4){0.f, 0.f, 0.f, 0.f};

  int iw = wave * 2;
  int r0 = iw * 16 + (lane >> 2);          // first staged row for this lane
  int gk0 = ((lane & 3) ^ ((r0 >> 1) & 3)) * 8;
  int r1 = r0 + 16;
  int gk1 = ((lane & 3) ^ ((r1 >> 1) & 3)) * 8;

#define STAGE(buf, k0)                                                   \
  do {                                                                   \
    gld16(&A[(long)(m0 + r0) * K + (k0) + gk0], &As[buf][iw * 512]);     \
    gld16(&Bt[(long)(n0 + r0) * K + (k0) + gk0], &Bs[buf][iw * 512]);    \
    gld16(&A[(long)(m0 + r1) * K + (k0) + gk1], &As[buf][iw * 512 + 512]); \
    gld16(&Bt[(long)(n0 + r1) * K + (k0) + gk1], &Bs[buf][iw * 512 + 512]); \
  } while (0)

  int NT = K >> 5;
  STAGE(0, 0);
  __syncthreads();  // drain tile-0 loads (once)
  int cur = 0;
  for (int t = 0; t < NT; ++t) {
    if (t + 1 < NT) STAGE(cur ^ 1, (t + 1) << 5);  // async, overlaps compute
    short8 af[2], bfr[8];
#pragma unroll
    for (int i = 0; i < 2; ++i) {
      int r = wm + i * 16 + l15;
      af[i] = *(short8*)&As[cur][r * 32 + ((quad ^ ((r >> 1) & 3)) << 3)];
    }
#pragma unroll
    for (int j = 0; j < 8; ++j) {
      int r = j * 16 + l15;
      bfr[j] = *(short8*)&Bs[cur][r * 32 + ((quad ^ ((r >> 1) & 3)) << 3)];
    }
#pragma unroll
    for (int i = 0; i < 2; ++i)
#pragma unroll
      for (int j = 0; j < 8; ++j)
        acc[i][j] = __builtin_amdgcn_mfma_f32_16x16x32_bf16(af[i], bfr[j], acc[i][j], 0, 0, 0);
    __syncthreads();  // drains next-tile loads; fences reads of buf[cur]
    cur ^= 1;
  }
#undef STAGE

  if (MODE == 0) {
#pragma unroll
    for (int i = 0; i < 2; ++i)
#pragma unroll
      for (int j = 0; j < 8; ++j)
#pragma unroll
        for (int r = 0; r < 4; ++r) {
          int row = m0 + wm + i * 16 + quad * 4 + r;
          int col = n0 + j * 16 + l15;
          C[(long)row * N + col] = acc[i][j][r];
        }
  } else {
    int head = n0 >> 7;  // 0..31 q, 32..39 k, 40..47 v (block-uniform)
    const float2* tb = (const float2*)tab;
    if (head < NH + NHK) {
      bool isq = head < NH;
      ushort_t* dst = isq ? (Qo + (long)head * SEQ * HD)
                          : (Ko + (long)(head - NH) * SEQ * HD);
      float sc = isq ? 0.08838834764831845f : 1.0f;  // fold 128^-0.5 into Q
#pragma unroll
      for (int i = 0; i < 2; ++i)
#pragma unroll
        for (int r = 0; r < 4; ++r) {
          int s = m0 + wm + i * 16 + quad * 4 + r;
#pragma unroll
          for (int j = 0; j < 4; ++j) {
            int d = j * 16 + l15;  // 0..63
            float2 cs = tb[s * 64 + d];
            float x1 = acc[i][j][r], x2 = acc[i][j + 4][r];
            dst[(long)s * HD + d] = f2bu((x1 * cs.x - x2 * cs.y) * sc);
            dst[(long)s * HD + d + 64] = f2bu((x2 * cs.x + x1 * cs.y) * sc);
          }
        }
    } else {
      int hk = head - NH - NHK;
      ushort_t* dst = Vo + (long)hk * HD * SEQ;  // V^T: [D][S]
#pragma unroll
      for (int i = 0; i < 2; ++i)
#pragma unroll
        for (int j = 0; j < 8; ++j)
#pragma unroll
          for (int r = 0; r < 4; ++r) {
            int s = m0 + wm + i * 16 + quad * 4 + r;
            int d = j * 16 + l15;
            dst[(long)d * SEQ + s] = f2bu(acc[i][j][r]);
          }
    }
  }
}

// ---------------------------------------------------------------------------
// Fallback GEMM (fp32 B transposed in-kernel) — used only if ws too small.
// ---------------------------------------------------------------------------
template <int MODE, typename TA>
__global__ __launch_bounds__(256, 2)
void gemm_kn(const TA* __restrict__ A,
             const float* __restrict__ B,
             float* __restrict__ C,
             const float* __restrict__ tab,
             ushort_t* __restrict__ Qo,
             ushort_t* __restrict__ Ko,
             ushort_t* __restrict__ Vo,
             int M, int N, int K) {
  __shared__ ushort_t As[128][40];
  __shared__ ushort_t Bs[128 * 32];
  int m0 = blockIdx.y * 128, n0 = blockIdx.x * 128;
  int tid = threadIdx.x;
  int lane = tid & 63, wave = tid >> 6;
  int wm = wave * 32;
  int l15 = lane & 15, quad = lane >> 4;
  f32x4 acc[2][8];
#pragma unroll
  for (int i = 0; i < 2; ++i)
#pragma unroll
    for (int j = 0; j < 8; ++j) acc[i][j] = (f32x4){0.f, 0.f, 0.f, 0.f};

  for (int k0 = 0; k0 < K; k0 += 32) {
    __syncthreads();
    if constexpr (sizeof(TA) == 2) {
#pragma unroll
      for (int it = 0; it < 2; ++it) {
        int v = tid + it * 256;
        int row = v >> 2, kc = (v & 3) * 8;
        *(short8*)&As[row][kc] =
            *(const short8*)&A[(long)(m0 + row) * K + k0 + kc];
      }
    } else {
#pragma unroll
      for (int it = 0; it < 4; ++it) {
        int v = tid + it * 256;
        int row = v >> 3, kc = (v & 7) * 4;
        f32x4 x = *(const f32x4*)&A[(long)(m0 + row) * K + k0 + kc];
        ushort4_t y;
#pragma unroll
        for (int u = 0; u < 4; ++u) y[u] = f2bu(x[u]);
        *(ushort4_t*)&As[row][kc] = y;
      }
    }
#pragma unroll
    for (int it = 0; it < 4; ++it) {
      int v = tid + it * 256;
      int kr = v >> 5, nc = (v & 31) * 4;
      f32x4 x = *(const f32x4*)&B[(long)(k0 + kr) * N + n0 + nc];
      int kg = (kr >> 3) << 3, ke = kr & 7;
#pragma unroll
      for (int u = 0; u < 4; ++u) {
        int n = nc + u;
        Bs[n * 32 + ((kg ^ (((n >> 2) & 3) << 3))) + ke] = f2bu(x[u]);
      }
    }
    __syncthreads();
    short8 af[2], bfr[8];
#pragma unroll
    for (int i = 0; i < 2; ++i) af[i] = *(short8*)&As[wm + i * 16 + l15][quad * 8];
#pragma unroll
    for (int j = 0; j < 8; ++j) {
      int n = j * 16 + l15;
      bfr[j] = *(short8*)&Bs[n * 32 + ((quad ^ ((n >> 2) & 3)) << 3)];
    }
#pragma unroll
    for (int i = 0; i < 2; ++i)
#pragma unroll
      for (int j = 0; j < 8; ++j)
        acc[i][j] = __builtin_amdgcn_mfma_f32_16x16x32_bf16(af[i], bfr[j], acc[i][j], 0, 0, 0);
  }

  if (MODE == 0) {
#pragma unroll
    for (int i = 0; i < 2; ++i)
#pragma unroll
      for (int j = 0; j < 8; ++j)
#pragma unroll
        for (int r = 0; r < 4; ++r) {
          int row = m0 + wm + i * 16 + quad * 4 + r;
          int col = n0 + j * 16 + l15;
          C[(long)row * N + col] = acc[i][j][r];
        }
  } else {
    int head = n0 >> 7;
    const float2* tb = (const float2*)tab;
    if (head < NH + NHK) {
      bool isq = head < NH;
      ushort_t* dst = isq ? (Qo + (long)head * SEQ * HD)
                          : (Ko + (long)(head - NH) * SEQ * HD);
      float sc = isq ? 0.08838834764831845f : 1.0f;
#pragma unroll
      for (int i = 0; i < 2; ++i)
#pragma unroll
        for (int r = 0; r < 4; ++r) {
          int s = m0 + wm + i * 16 + quad * 4 + r;
#pragma unroll
          for (int j = 0; j < 4; ++j) {
            int d = j * 16 + l15;
            float2 cs = tb[s * 64 + d];
            float x1 = acc[i][j][r], x2 = acc[i][j + 4][r];
            dst[(long)s * HD + d] = f2bu((x1 * cs.x - x2 * cs.y) * sc);
            dst[(long)s * HD + d + 64] = f2bu((x2 * cs.x + x1 * cs.y) * sc);
          }
        }
    } else {
      int hk = head - NH - NHK;
      ushort_t* dst = Vo + (long)hk * HD * SEQ;
#pragma unroll
      for (int i = 0; i < 2; ++i)
#pragma unroll
        for (int j = 0; j < 8; ++j)
#pragma unroll
          for (int r = 0; r < 4; ++r) {
            int s = m0 + wm + i * 16 + quad * 4 + r;
            int d = j * 16 + l15;
            dst[(long)d * SEQ + s] = f2bu(acc[i][j][r]);
          }
    }
  }
}

// ---------- flash attention: 64 q / block (4 waves x 16), 64-key chunks ------
// KVBLK=64 + LPT (heaviest causal blocks first).
__global__ __launch_bounds__(256, 2) void attn_k(const ushort_t* __restrict__ Q,
                                                 const ushort_t* __restrict__ Kg,
                                                 const ushort_t* __restrict__ Vt,
                                                 ushort_t* __restrict__ Aout) {
  __shared__ ushort_t Ks[64][136];    // [key][d]   (+8 pad)
  __shared__ ushort_t Vs[128][72];    // [d][key]   (+8 pad)
  __shared__ ushort_t Ps[4][16][72];  // per-wave P tile [q][key] (+8 pad)
  int qt = ((int)gridDim.x - 1 - blockIdx.x) * 64;  // LPT order
  int h = blockIdx.y;
  int hk = h >> 2;
  const ushort_t* Qh = Q + (long)h * SEQ * HD;
  const ushort_t* Kh = Kg + (long)hk * SEQ * HD;
  const ushort_t* Vh = Vt + (long)hk * HD * SEQ;
  int tid = threadIdx.x, lane = tid & 63, wave = tid >> 6;
  int l15 = lane & 15, quad = lane >> 4;
  int qw = qt + wave * 16;
  short8 qf[4];
#pragma unroll
  for (int c = 0; c < 4; ++c)
    qf[c] = *(const short8*)&Qh[(long)(qw + l15) * HD + c * 32 + quad * 8];
  f32x4 O[8];
#pragma unroll
  for (int dt = 0; dt < 8; ++dt) O[dt] = (f32x4){0.f, 0.f, 0.f, 0.f};
  float mrow[4], lrow[4];
#pragma unroll
  for (int r = 0; r < 4; ++r) { mrow[r] = -1e30f; lrow[r] = 0.f; }
  int kend = qt + 64;
  for (int kc = 0; kc < kend; kc += 64) {
    __syncthreads();
#pragma unroll
    for (int i = 0; i < 4; ++i) {
      int v = tid + i * 256;
      int kr = v >> 4, dc = (v & 15) * 8;
      *(short8*)&Ks[kr][dc] = *(const short8*)&Kh[(long)(kc + kr) * HD + dc];
    }
#pragma unroll
    for (int i = 0; i < 4; ++i) {
      int v = tid + i * 256;
      int dr = v >> 3, kcol = (v & 7) * 8;
      *(short8*)&Vs[dr][kcol] = *(const short8*)&Vh[(long)dr * SEQ + kc + kcol];
    }
    __syncthreads();
    bool active = (kc <= qw + 15);  // wave-uniform
    if (active) {
      f32x4 S[4];
#pragma unroll
      for (int t = 0; t < 4; ++t) S[t] = (f32x4){0.f, 0.f, 0.f, 0.f};
#pragma unroll
      for (int c = 0; c < 4; ++c) {
#pragma unroll
        for (int t = 0; t < 4; ++t) {
          short8 kf = *(short8*)&Ks[t * 16 + l15][c * 32 + quad * 8];
          S[t] = __builtin_amdgcn_mfma_f32_16x16x32_bf16(qf[c], kf, S[t], 0, 0, 0);
        }
      }
#pragma unroll
      for (int r = 0; r < 4; ++r) {
        int qrow = qw + quad * 4 + r;
        float vv[4];
#pragma unroll
        for (int t = 0; t < 4; ++t)
          vv[t] = (kc + t * 16 + l15 <= qrow) ? S[t][r] : -1e30f;
        float mx = fmaxf(fmaxf(vv[0], vv[1]), fmaxf(vv[2], vv[3]));
        mx = fmaxf(mx, __shfl_xor(mx, 1, 64));
        mx = fmaxf(mx, __shfl_xor(mx, 2, 64));
        mx = fmaxf(mx, __shfl_xor(mx, 4, 64));
        mx = fmaxf(mx, __shfl_xor(mx, 8, 64));
        float mnew = fmaxf(mrow[r], mx);
        float alpha = __expf(mrow[r] - mnew);
        float p[4];
#pragma unroll
        for (int t = 0; t < 4; ++t) p[t] = __expf(vv[t] - mnew);
        float rs = (p[0] + p[1]) + (p[2] + p[3]);
        rs += __shfl_xor(rs, 1, 64);
        rs += __shfl_xor(rs, 2, 64);
        rs += __shfl_xor(rs, 4, 64);
        rs += __shfl_xor(rs, 8, 64);
        lrow[r] = lrow[r] * alpha + rs;
        mrow[r] = mnew;
#pragma unroll
        for (int dt = 0; dt < 8; ++dt) O[dt][r] *= alpha;
#pragma unroll
        for (int t = 0; t < 4; ++t)
          Ps[wave][quad * 4 + r][t * 16 + l15] = f2bu(p[t]);
      }
    }
    __syncthreads();
    if (active) {
      short8 pf0 = *(short8*)&Ps[wave][l15][quad * 8];
      short8 pf1 = *(short8*)&Ps[wave][l15][32 + quad * 8];
#pragma unroll
      for (int dt = 0; dt < 8; ++dt) {
        short8 vf0 = *(short8*)&Vs[dt * 16 + l15][quad * 8];
        short8 vf1 = *(short8*)&Vs[dt * 16 + l15][32 + quad * 8];
        O[dt] = __builtin_amdgcn_mfma_f32_16x16x32_bf16(pf0, vf0, O[dt], 0, 0, 0);
        O[dt] = __builtin_amdgcn_mfma_f32_16x16x32_bf16(pf1, vf1, O[dt], 0, 0, 0);
      }
    }
  }
#pragma unroll
  for (int dt = 0; dt < 8; ++dt)
#pragma unroll
    for (int r = 0; r < 4; ++r) {
      int q = qw + quad * 4 + r;
      float o = O[dt][r] / lrow[r];
      Aout[(long)q * (NH * HD) + h * HD + dt * 16 + l15] = f2bu(o);
    }
}

extern "C" void kernel_launch(void* const* d_in, const int* in_sizes, int n_in,
                              void* d_out, int out_size, void* d_ws, size_t ws_size,
                              hipStream_t stream) {
  const int* positions = (const int*)d_in[0];
  const float* hidden = (const float*)d_in[1];
  const float* w_qkv = (const float*)d_in[2];
  const float* w_o = (const float*)d_in[3];
  char* ws = (char*)d_ws;
  // Base layout (40 MB, proven):
  ushort_t* Qb = (ushort_t*)(ws + 0L);           // [NH,S,D]   16777216
  ushort_t* Kb = (ushort_t*)(ws + 16777216L);    // [NHK,S,D]   4194304
  ushort_t* Vtb = (ushort_t*)(ws + 20971520L);   // [NHK,D,S]   4194304
  ushort_t* attno = (ushort_t*)(ws + 25165824L); // [S, NH*D]  16777216
  float* tab = (float*)attno;                    // 1 MB, dead before attn_k
  // Extended layout (needs 152 MB total):
  ushort_t* hb16 = (ushort_t*)(ws + 41943040L);   // [NB,S,HID]   33554432
  ushort_t* wqkvT = (ushort_t*)(ws + 75497472L);  // [NQKV,HID]   50331648
  ushort_t* woT = (ushort_t*)(ws + 125829120L);   // [HID,HID]    33554432
  float* outf = (float*)d_out;
  bool big = ws_size >= 159383552ULL;

  if (big) {
    h2b_k<<<dim3((NB * SEQ * HID) / (256 * 8)), 256, 0, stream>>>(hidden, hb16);
    wt_k<<<dim3(NQKV / 64, HID / 64), 256, 0, stream>>>(w_qkv, wqkvT, HID, NQKV);
    wt_k<<<dim3(HID / 64, HID / 64), 256, 0, stream>>>(w_o, woT, HID, HID);
  }
  for (int b = 0; b < NB; ++b) {
    rope_tab_k<<<dim3((SEQ * 64) / 256), 256, 0, stream>>>(positions, tab);
    if (big) {
      gemm_bt<1><<<dim3(NQKV / 128, SEQ / 128), 256, 0, stream>>>(
          hb16 + (long)b * SEQ * HID, wqkvT, nullptr, tab, Qb, Kb, Vtb,
          SEQ, NQKV, HID);
    } else {
      gemm_kn<1, float><<<dim3(NQKV / 128, SEQ / 128), 256, 0, stream>>>(
          hidden + (long)b * SEQ * HID, w_qkv, nullptr, tab, Qb, Kb, Vtb,
          SEQ, NQKV, HID);
    }
    attn_k<<<dim3(SEQ / 64, NH), 256, 0, stream>>>(Qb, Kb, Vtb, attno);
    if (big) {
      gemm_bt<0><<<dim3(HID / 128, SEQ / 128), 256, 0, stream>>>(
          attno, woT, outf + (long)b * SEQ * HID, nullptr, nullptr, nullptr,
          nullptr, SEQ, HID, HID);
    } else {
      gemm_kn<0, ushort_t><<<dim3(HID / 128, SEQ / 128), 256, 0, stream>>>(
          attno, w_o, outf + (long)b * SEQ * HID, nullptr, nullptr, nullptr,
          nullptr, SEQ, HID, HID);
    }
  }
}

// Round 8
// 1006.031 us; speedup vs baseline: 1.1509x; 1.0079x over previous
//
#include <hip/hip_runtime.h>

typedef unsigned short ushort_t;
typedef __attribute__((ext_vector_type(8))) short short8;
typedef __attribute__((ext_vector_type(4))) unsigned short ushort4_t;
typedef __attribute__((ext_vector_type(4))) float f32x4;

#define NH 32
#define NHK 8
#define HD 128
#define HID 4096
#define NB 2
#define SEQ 2048
#define NQKV ((NH + 2 * NHK) * HD)  // 6144

static __device__ inline ushort_t f2bu(float x) {
  unsigned u = __builtin_bit_cast(unsigned, x);
  unsigned r = (u + 0x7FFFu + ((u >> 16) & 1u)) >> 16;  // RNE
  return (ushort_t)r;
}

// async global->LDS, 16B per lane. LDS dest = wave-uniform base + lane*16.
typedef __attribute__((address_space(1))) void gvoid;
typedef __attribute__((address_space(3))) void lvoid;
static __device__ inline void gld16(const void* g, void* l) {
  __builtin_amdgcn_global_load_lds((gvoid*)g, (lvoid*)l, 16, 0, 0);
}

// ---------- RoPE cos/sin table: tab[s][d] = {cos,sin}(pos[s]*10000^(-d/64)) --
// Lives in the (then-dead) attno region: zero extra ws. Regenerated per batch.
__global__ void rope_tab_k(const int* __restrict__ positions, float* __restrict__ tab) {
  int i = blockIdx.x * 256 + threadIdx.x;  // [0, SEQ*64)
  int s = i >> 6, d = i & 63;
  float pos = (float)positions[s];
  float f = pos * exp2f(-0.20762050593046014f * (float)d);
  tab[2 * i] = cosf(f);
  tab[2 * i + 1] = sinf(f);
}

// ---------- fp32 -> bf16 bulk convert (hidden states) ------------------------
__global__ void h2b_k(const float* __restrict__ in, ushort_t* __restrict__ out) {
  long i = ((long)blockIdx.x * 256 + threadIdx.x) * 8;
  f32x4 a = *(const f32x4*)&in[i];
  f32x4 b = *(const f32x4*)&in[i + 4];
  ushort4_t ya, yb;
#pragma unroll
  for (int u = 0; u < 4; ++u) { ya[u] = f2bu(a[u]); yb[u] = f2bu(b[u]); }
  *(ushort4_t*)&out[i] = ya;
  *(ushort4_t*)&out[i + 4] = yb;
}

// ---------- weight transpose+convert: out[n][k] bf16 <- in[k][n] f32 ---------
__global__ void wt_k(const float* __restrict__ in, ushort_t* __restrict__ out,
                     int K, int N) {
  __shared__ ushort_t T[64][72];  // [k][n] bf16, +8 pad
  int n0 = blockIdx.x * 64, k0 = blockIdx.y * 64;
  int t = threadIdx.x;
  int kr = t >> 4, nc = (t & 15) * 4;
#pragma unroll
  for (int p = 0; p < 4; ++p) {
    int k = kr + p * 16;
    f32x4 x = *(const f32x4*)&in[(long)(k0 + k) * N + n0 + nc];
    ushort4_t y;
#pragma unroll
    for (int u = 0; u < 4; ++u) y[u] = f2bu(x[u]);
    *(ushort4_t*)&T[k][nc] = y;
  }
  __syncthreads();
  int n = t >> 2, kc = (t & 3) * 16;
  ushort_t tmp[16];
#pragma unroll
  for (int j = 0; j < 16; ++j) tmp[j] = T[kc + j][n];
  *(short8*)&out[(long)(n0 + n) * K + k0 + kc] = *(short8*)&tmp[0];
  *(short8*)&out[(long)(n0 + n) * K + k0 + kc + 8] = *(short8*)&tmp[8];
}

// ---------------------------------------------------------------------------
// gemm_bt: C[M,N] = A[M,K] @ Bt[N,K]^T, both bf16.
// 2-phase double-buffered K-loop: stage tile t+1 via global_load_lds BEFORE
// computing tile t; single __syncthreads per K-step. launch_bounds(256,2)
// keeps the 256-VGPR budget without capping occupancy (waves_per_eu(2,2)
// max-cap cost 17.8% vs 29.7% occupancy — round 6/7 A/B).
// ---------------------------------------------------------------------------
template <int MODE>
__global__ __launch_bounds__(256, 2)
void gemm_bt(const ushort_t* __restrict__ A,
             const ushort_t* __restrict__ Bt,
             float* __restrict__ C,
             const float* __restrict__ tab,
             ushort_t* __restrict__ Qo,
             ushort_t* __restrict__ Ko,
             ushort_t* __restrict__ Vo,
             int M, int N, int K) {
  __shared__ ushort_t As[2][128 * 32];  // 2 x 8 KB, granule-swizzled
  __shared__ ushort_t Bs[2][128 * 32];  // 2 x 8 KB
  int m0 = blockIdx.y * 128, n0 = blockIdx.x * 128;
  int tid = threadIdx.x;
  int lane = tid & 63, wave = tid >> 6;
  int wm = wave * 32;
  int l15 = lane & 15, quad = lane >> 4;
  f32x4 acc[2][8];
#pragma unroll
  for (int i = 0; i < 2; ++i)
#pragma unroll
    for (int j = 0; j < 8; ++j) acc[i][j] = (f32x4){0.f, 0.f, 0.f, 0.f};

  int iw = wave * 2;
  int r0 = iw * 16 + (lane >> 2);          // first staged row for this lane
  int gk0 = ((lane & 3) ^ ((r0 >> 1) & 3)) * 8;
  int r1 = r0 + 16;
  int gk1 = ((lane & 3) ^ ((r1 >> 1) & 3)) * 8;

#define STAGE(buf, k0)                                                   \
  do {                                                                   \
    gld16(&A[(long)(m0 + r0) * K + (k0) + gk0], &As[buf][iw * 512]);     \
    gld16(&Bt[(long)(n0 + r0) * K + (k0) + gk0], &Bs[buf][iw * 512]);    \
    gld16(&A[(long)(m0 + r1) * K + (k0) + gk1], &As[buf][iw * 512 + 512]); \
    gld16(&Bt[(long)(n0 + r1) * K + (k0) + gk1], &Bs[buf][iw * 512 + 512]); \
  } while (0)

  int NT = K >> 5;
  STAGE(0, 0);
  __syncthreads();  // drain tile-0 loads (once)
  int cur = 0;
  for (int t = 0; t < NT; ++t) {
    if (t + 1 < NT) STAGE(cur ^ 1, (t + 1) << 5);  // async, overlaps compute
    short8 af[2], bfr[8];
#pragma unroll
    for (int i = 0; i < 2; ++i) {
      int r = wm + i * 16 + l15;
      af[i] = *(short8*)&As[cur][r * 32 + ((quad ^ ((r >> 1) & 3)) << 3)];
    }
#pragma unroll
    for (int j = 0; j < 8; ++j) {
      int r = j * 16 + l15;
      bfr[j] = *(short8*)&Bs[cur][r * 32 + ((quad ^ ((r >> 1) & 3)) << 3)];
    }
#pragma unroll
    for (int i = 0; i < 2; ++i)
#pragma unroll
      for (int j = 0; j < 8; ++j)
        acc[i][j] = __builtin_amdgcn_mfma_f32_16x16x32_bf16(af[i], bfr[j], acc[i][j], 0, 0, 0);
    __syncthreads();  // drains next-tile loads; fences reads of buf[cur]
    cur ^= 1;
  }
#undef STAGE

  if (MODE == 0) {
#pragma unroll
    for (int i = 0; i < 2; ++i)
#pragma unroll
      for (int j = 0; j < 8; ++j)
#pragma unroll
        for (int r = 0; r < 4; ++r) {
          int row = m0 + wm + i * 16 + quad * 4 + r;
          int col = n0 + j * 16 + l15;
          C[(long)row * N + col] = acc[i][j][r];
        }
  } else {
    int head = n0 >> 7;  // 0..31 q, 32..39 k, 40..47 v (block-uniform)
    const float2* tb = (const float2*)tab;
    if (head < NH + NHK) {
      bool isq = head < NH;
      ushort_t* dst = isq ? (Qo + (long)head * SEQ * HD)
                          : (Ko + (long)(head - NH) * SEQ * HD);
      float sc = isq ? 0.08838834764831845f : 1.0f;  // fold 128^-0.5 into Q
#pragma unroll
      for (int i = 0; i < 2; ++i)
#pragma unroll
        for (int r = 0; r < 4; ++r) {
          int s = m0 + wm + i * 16 + quad * 4 + r;
#pragma unroll
          for (int j = 0; j < 4; ++j) {
            int d = j * 16 + l15;  // 0..63
            float2 cs = tb[s * 64 + d];
            float x1 = acc[i][j][r], x2 = acc[i][j + 4][r];
            dst[(long)s * HD + d] = f2bu((x1 * cs.x - x2 * cs.y) * sc);
            dst[(long)s * HD + d + 64] = f2bu((x2 * cs.x + x1 * cs.y) * sc);
          }
        }
    } else {
      int hk = head - NH - NHK;
      ushort_t* dst = Vo + (long)hk * HD * SEQ;  // V^T: [D][S]
#pragma unroll
      for (int i = 0; i < 2; ++i)
#pragma unroll
        for (int j = 0; j < 8; ++j)
#pragma unroll
          for (int r = 0; r < 4; ++r) {
            int s = m0 + wm + i * 16 + quad * 4 + r;
            int d = j * 16 + l15;
            dst[(long)d * SEQ + s] = f2bu(acc[i][j][r]);
          }
    }
  }
}

// ---------------------------------------------------------------------------
// Fallback GEMM (fp32 B transposed in-kernel) — used only if ws too small.
// ---------------------------------------------------------------------------
template <int MODE, typename TA>
__global__ __launch_bounds__(256, 2)
void gemm_kn(const TA* __restrict__ A,
             const float* __restrict__ B,
             float* __restrict__ C,
             const float* __restrict__ tab,
             ushort_t* __restrict__ Qo,
             ushort_t* __restrict__ Ko,
             ushort_t* __restrict__ Vo,
             int M, int N, int K) {
  __shared__ ushort_t As[128][40];
  __shared__ ushort_t Bs[128 * 32];
  int m0 = blockIdx.y * 128, n0 = blockIdx.x * 128;
  int tid = threadIdx.x;
  int lane = tid & 63, wave = tid >> 6;
  int wm = wave * 32;
  int l15 = lane & 15, quad = lane >> 4;
  f32x4 acc[2][8];
#pragma unroll
  for (int i = 0; i < 2; ++i)
#pragma unroll
    for (int j = 0; j < 8; ++j) acc[i][j] = (f32x4){0.f, 0.f, 0.f, 0.f};

  for (int k0 = 0; k0 < K; k0 += 32) {
    __syncthreads();
    if constexpr (sizeof(TA) == 2) {
#pragma unroll
      for (int it = 0; it < 2; ++it) {
        int v = tid + it * 256;
        int row = v >> 2, kc = (v & 3) * 8;
        *(short8*)&As[row][kc] =
            *(const short8*)&A[(long)(m0 + row) * K + k0 + kc];
      }
    } else {
#pragma unroll
      for (int it = 0; it < 4; ++it) {
        int v = tid + it * 256;
        int row = v >> 3, kc = (v & 7) * 4;
        f32x4 x = *(const f32x4*)&A[(long)(m0 + row) * K + k0 + kc];
        ushort4_t y;
#pragma unroll
        for (int u = 0; u < 4; ++u) y[u] = f2bu(x[u]);
        *(ushort4_t*)&As[row][kc] = y;
      }
    }
#pragma unroll
    for (int it = 0; it < 4; ++it) {
      int v = tid + it * 256;
      int kr = v >> 5, nc = (v & 31) * 4;
      f32x4 x = *(const f32x4*)&B[(long)(k0 + kr) * N + n0 + nc];
      int kg = (kr >> 3) << 3, ke = kr & 7;
#pragma unroll
      for (int u = 0; u < 4; ++u) {
        int n = nc + u;
        Bs[n * 32 + ((kg ^ (((n >> 2) & 3) << 3))) + ke] = f2bu(x[u]);
      }
    }
    __syncthreads();
    short8 af[2], bfr[8];
#pragma unroll
    for (int i = 0; i < 2; ++i) af[i] = *(short8*)&As[wm + i * 16 + l15][quad * 8];
#pragma unroll
    for (int j = 0; j < 8; ++j) {
      int n = j * 16 + l15;
      bfr[j] = *(short8*)&Bs[n * 32 + ((quad ^ ((n >> 2) & 3)) << 3)];
    }
#pragma unroll
    for (int i = 0; i < 2; ++i)
#pragma unroll
      for (int j = 0; j < 8; ++j)
        acc[i][j] = __builtin_amdgcn_mfma_f32_16x16x32_bf16(af[i], bfr[j], acc[i][j], 0, 0, 0);
  }

  if (MODE == 0) {
#pragma unroll
    for (int i = 0; i < 2; ++i)
#pragma unroll
      for (int j = 0; j < 8; ++j)
#pragma unroll
        for (int r = 0; r < 4; ++r) {
          int row = m0 + wm + i * 16 + quad * 4 + r;
          int col = n0 + j * 16 + l15;
          C[(long)row * N + col] = acc[i][j][r];
        }
  } else {
    int head = n0 >> 7;
    const float2* tb = (const float2*)tab;
    if (head < NH + NHK) {
      bool isq = head < NH;
      ushort_t* dst = isq ? (Qo + (long)head * SEQ * HD)
                          : (Ko + (long)(head - NH) * SEQ * HD);
      float sc = isq ? 0.08838834764831845f : 1.0f;
#pragma unroll
      for (int i = 0; i < 2; ++i)
#pragma unroll
        for (int r = 0; r < 4; ++r) {
          int s = m0 + wm + i * 16 + quad * 4 + r;
#pragma unroll
          for (int j = 0; j < 4; ++j) {
            int d = j * 16 + l15;
            float2 cs = tb[s * 64 + d];
            float x1 = acc[i][j][r], x2 = acc[i][j + 4][r];
            dst[(long)s * HD + d] = f2bu((x1 * cs.x - x2 * cs.y) * sc);
            dst[(long)s * HD + d + 64] = f2bu((x2 * cs.x + x1 * cs.y) * sc);
          }
        }
    } else {
      int hk = head - NH - NHK;
      ushort_t* dst = Vo + (long)hk * HD * SEQ;
#pragma unroll
      for (int i = 0; i < 2; ++i)
#pragma unroll
        for (int j = 0; j < 8; ++j)
#pragma unroll
          for (int r = 0; r < 4; ++r) {
            int s = m0 + wm + i * 16 + quad * 4 + r;
            int d = j * 16 + l15;
            dst[(long)d * SEQ + s] = f2bu(acc[i][j][r]);
          }
    }
  }
}

// ---------- flash attention: 128 q / block (8 waves x 16), 64-key chunks -----
// QBLK=128: halves chunk-units (staging bytes + barriers per unit work) vs
// the 64-q version (179.7 us, MfmaUtil 8%, Occupancy 14.4% — overhead-bound).
// T14 async-STAGE: global->reg prefetch of chunk t+1 issued before compute,
// ds_write after the barrier (manual A/B reg sets — no runtime reg indexing).
// T5 setprio around MFMA clusters. LPT: heaviest causal blocks first.
__global__ __launch_bounds__(512, 2) void attn_k(const ushort_t* __restrict__ Q,
                                                 const ushort_t* __restrict__ Kg,
                                                 const ushort_t* __restrict__ Vt,
                                                 ushort_t* __restrict__ Aout) {
  __shared__ ushort_t Ks[64][136];    // [key][d]   (+8 pad)  17.4 KB
  __shared__ ushort_t Vs[128][72];    // [d][key]   (+8 pad)  18.4 KB
  __shared__ ushort_t Ps[8][16][72];  // per-wave P tile [q][key] 18.4 KB
  int qt = ((int)gridDim.x - 1 - blockIdx.x) * 128;  // LPT order
  int h = blockIdx.y;
  int hk = h >> 2;
  const ushort_t* Qh = Q + (long)h * SEQ * HD;
  const ushort_t* Kh = Kg + (long)hk * SEQ * HD;
  const ushort_t* Vh = Vt + (long)hk * HD * SEQ;
  int tid = threadIdx.x, lane = tid & 63, wave = tid >> 6;
  int l15 = lane & 15, quad = lane >> 4;
  int qw = qt + wave * 16;
  // staging coords (512 threads, 2 granules each for K and V)
  int skr0 = tid >> 4, sdc0 = (tid & 15) * 8;
  int skr1 = (tid + 512) >> 4, sdc1 = ((tid + 512) & 15) * 8;
  int sdr0 = tid >> 3, skc0 = (tid & 7) * 8;
  int sdr1 = (tid + 512) >> 3, skc1 = ((tid + 512) & 7) * 8;
  short8 kra[2], vra[2], krb[2], vrb[2];

#define LOADREG(KR, VR, kcc)                                              \
  do {                                                                    \
    KR[0] = *(const short8*)&Kh[(long)((kcc) + skr0) * HD + sdc0];        \
    KR[1] = *(const short8*)&Kh[(long)((kcc) + skr1) * HD + sdc1];        \
    VR[0] = *(const short8*)&Vh[(long)sdr0 * SEQ + (kcc) + skc0];         \
    VR[1] = *(const short8*)&Vh[(long)sdr1 * SEQ + (kcc) + skc1];         \
  } while (0)

#define STORELDS(KR, VR)                                                  \
  do {                                                                    \
    *(short8*)&Ks[skr0][sdc0] = KR[0];                                    \
    *(short8*)&Ks[skr1][sdc1] = KR[1];                                    \
    *(short8*)&Vs[sdr0][skc0] = VR[0];                                    \
    *(short8*)&Vs[sdr1][skc1] = VR[1];                                    \
  } while (0)

  short8 qf[4];
#pragma unroll
  for (int c = 0; c < 4; ++c)
    qf[c] = *(const short8*)&Qh[(long)(qw + l15) * HD + c * 32 + quad * 8];
  f32x4 O[8];
#pragma unroll
  for (int dt = 0; dt < 8; ++dt) O[dt] = (f32x4){0.f, 0.f, 0.f, 0.f};
  float mrow[4], lrow[4];
#pragma unroll
  for (int r = 0; r < 4; ++r) { mrow[r] = -1e30f; lrow[r] = 0.f; }
  int kend = qt + 128;

#define COMPUTE(kcc)                                                        \
  do {                                                                      \
    bool active = ((kcc) <= qw + 15); /* wave-uniform */                    \
    if (active) {                                                           \
      f32x4 S[4];                                                           \
      _Pragma("unroll") for (int t = 0; t < 4; ++t)                         \
          S[t] = (f32x4){0.f, 0.f, 0.f, 0.f};                               \
      __builtin_amdgcn_s_setprio(1);                                        \
      _Pragma("unroll") for (int c = 0; c < 4; ++c) {                       \
        _Pragma("unroll") for (int t = 0; t < 4; ++t) {                     \
          short8 kf = *(short8*)&Ks[t * 16 + l15][c * 32 + quad * 8];       \
          S[t] = __builtin_amdgcn_mfma_f32_16x16x32_bf16(qf[c], kf, S[t], 0, 0, 0); \
        }                                                                   \
      }                                                                     \
      __builtin_amdgcn_s_setprio(0);                                        \
      _Pragma("unroll") for (int r = 0; r < 4; ++r) {                       \
        int qrow = qw + quad * 4 + r;                                       \
        float vv[4];                                                        \
        _Pragma("unroll") for (int t = 0; t < 4; ++t)                       \
            vv[t] = ((kcc) + t * 16 + l15 <= qrow) ? S[t][r] : -1e30f;      \
        float mx = fmaxf(fmaxf(vv[0], vv[1]), fmaxf(vv[2], vv[3]));         \
        mx = fmaxf(mx, __shfl_xor(mx, 1, 64));                              \
        mx = fmaxf(mx, __shfl_xor(mx, 2, 64));                              \
        mx = fmaxf(mx, __shfl_xor(mx, 4, 64));                              \
        mx = fmaxf(mx, __shfl_xor(mx, 8, 64));                              \
        float mnew = fmaxf(mrow[r], mx);                                    \
        float alpha = __expf(mrow[r] - mnew);                               \
        float p[4];                                                         \
        _Pragma("unroll") for (int t = 0; t < 4; ++t)                       \
            p[t] = __expf(vv[t] - mnew);                                    \
        float rs = (p[0] + p[1]) + (p[2] + p[3]);                           \
        rs += __shfl_xor(rs, 1, 64);                                        \
        rs += __shfl_xor(rs, 2, 64);                                        \
        rs += __shfl_xor(rs, 4, 64);                                        \
        rs += __shfl_xor(rs, 8, 64);                                        \
        lrow[r] = lrow[r] * alpha + rs;                                     \
        mrow[r] = mnew;                                                     \
        _Pragma("unroll") for (int dt = 0; dt < 8; ++dt) O[dt][r] *= alpha; \
        _Pragma("unroll") for (int t = 0; t < 4; ++t)                       \
            Ps[wave][quad * 4 + r][t * 16 + l15] = f2bu(p[t]);              \
      }                                                                     \
    }                                                                       \
    __syncthreads(); /* P visible; Ks/Vs reads done */                      \
    if (active) {                                                           \
      short8 pf0 = *(short8*)&Ps[wave][l15][quad * 8];                      \
      short8 pf1 = *(short8*)&Ps[wave][l15][32 + quad * 8];                 \
      __builtin_amdgcn_s_setprio(1);                                        \
      _Pragma("unroll") for (int dt = 0; dt < 8; ++dt) {                    \
        short8 vf0 = *(short8*)&Vs[dt * 16 + l15][quad * 8];                \
        short8 vf1 = *(short8*)&Vs[dt * 16 + l15][32 + quad * 8];           \
        O[dt] = __builtin_amdgcn_mfma_f32_16x16x32_bf16(pf0, vf0, O[dt], 0, 0, 0); \
        O[dt] = __builtin_amdgcn_mfma_f32_16x16x32_bf16(pf1, vf1, O[dt], 0, 0, 0); \
      }                                                                     \
      __builtin_amdgcn_s_setprio(0);                                        \
    }                                                                       \
  } while (0)

  LOADREG(kra, vra, 0);
  int kc = 0;
  for (;;) {
    // --- iteration using reg-set A ---
    __syncthreads();  // all waves done reading Ks/Vs (prev chunk)
    STORELDS(kra, vra);
    if (kc + 64 < kend) LOADREG(krb, vrb, kc + 64);  // hide under compute
    __syncthreads();  // staging visible
    COMPUTE(kc);
    kc += 64;
    if (kc >= kend) break;
    // --- iteration using reg-set B ---
    __syncthreads();
    STORELDS(krb, vrb);
    if (kc + 64 < kend) LOADREG(kra, vra, kc + 64);
    __syncthreads();
    COMPUTE(kc);
    kc += 64;
    if (kc >= kend) break;
  }
#undef LOADREG
#undef STORELDS
#undef COMPUTE

#pragma unroll
  for (int dt = 0; dt < 8; ++dt)
#pragma unroll
    for (int r = 0; r < 4; ++r) {
      int q = qw + quad * 4 + r;
      float o = O[dt][r] / lrow[r];
      Aout[(long)q * (NH * HD) + h * HD + dt * 16 + l15] = f2bu(o);
    }
}

extern "C" void kernel_launch(void* const* d_in, const int* in_sizes, int n_in,
                              void* d_out, int out_size, void* d_ws, size_t ws_size,
                              hipStream_t stream) {
  const int* positions = (const int*)d_in[0];
  const float* hidden = (const float*)d_in[1];
  const float* w_qkv = (const float*)d_in[2];
  const float* w_o = (const float*)d_in[3];
  char* ws = (char*)d_ws;
  // Base layout (40 MB, proven):
  ushort_t* Qb = (ushort_t*)(ws + 0L);           // [NH,S,D]   16777216
  ushort_t* Kb = (ushort_t*)(ws + 16777216L);    // [NHK,S,D]   4194304
  ushort_t* Vtb = (ushort_t*)(ws + 20971520L);   // [NHK,D,S]   4194304
  ushort_t* attno = (ushort_t*)(ws + 25165824L); // [S, NH*D]  16777216
  float* tab = (float*)attno;                    // 1 MB, dead before attn_k
  // Extended layout (needs 152 MB total):
  ushort_t* hb16 = (ushort_t*)(ws + 41943040L);   // [NB,S,HID]   33554432
  ushort_t* wqkvT = (ushort_t*)(ws + 75497472L);  // [NQKV,HID]   50331648
  ushort_t* woT = (ushort_t*)(ws + 125829120L);   // [HID,HID]    33554432
  float* outf = (float*)d_out;
  bool big = ws_size >= 159383552ULL;

  if (big) {
    h2b_k<<<dim3((NB * SEQ * HID) / (256 * 8)), 256, 0, stream>>>(hidden, hb16);
    wt_k<<<dim3(NQKV / 64, HID / 64), 256, 0, stream>>>(w_qkv, wqkvT, HID, NQKV);
    wt_k<<<dim3(HID / 64, HID / 64), 256, 0, stream>>>(w_o, woT, HID, HID);
  }
  for (int b = 0; b < NB; ++b) {
    rope_tab_k<<<dim3((SEQ * 64) / 256), 256, 0, stream>>>(positions, tab);
    if (big) {
      gemm_bt<1><<<dim3(NQKV / 128, SEQ / 128), 256, 0, stream>>>(
          hb16 + (long)b * SEQ * HID, wqkvT, nullptr, tab, Qb, Kb, Vtb,
          SEQ, NQKV, HID);
    } else {
      gemm_kn<1, float><<<dim3(NQKV / 128, SEQ / 128), 256, 0, stream>>>(
          hidden + (long)b * SEQ * HID, w_qkv, nullptr, tab, Qb, Kb, Vtb,
          SEQ, NQKV, HID);
    }
    attn_k<<<dim3(SEQ / 128, NH), 512, 0, stream>>>(Qb, Kb, Vtb, attno);
    if (big) {
      gemm_bt<0><<<dim3(HID / 128, SEQ / 128), 256, 0, stream>>>(
          attno, woT, outf + (long)b * SEQ * HID, nullptr, nullptr, nullptr,
          nullptr, SEQ, HID, HID);
    } else {
      gemm_kn<0, ushort_t><<<dim3(HID / 128, SEQ / 128), 256, 0, stream>>>(
          attno, w_o, outf + (long)b * SEQ * HID, nullptr, nullptr, nullptr,
          nullptr, SEQ, HID, HID);
    }
  }
}